// Round 6
// baseline (514.709 us; speedup 1.0000x reference)
//
#include <hip/hip_runtime.h>
#include <math.h>

#define B_ 512
#define I_ 512
#define O_ 512
#define BO_ (B_*O_)

// fast path
#define TB 64                  // b per block
#define TO 16                  // o per block
#define KI 16                  // i per chunk
#define ZN 8                   // i-splits
#define NIZ (I_/ZN)            // 64 i per block
#define NCHZ (NIZ/KI)          // 4 chunks
#define LXS (TB + 4)           // 68: padded x rows

#define SQH    0.84932180028801904f   // sqrt(0.5*log2(e))
#define MN_   (-1.2023679775792928f)  // -(2 ln2) * NORM
#define NN_   (-0.86732507058407750f) // -NORM
#define NORM_  (0.86732507058407750f)
#define K_EXP  (-0.72134752044448170f)
#define BN_EPS (1e-5f)
#define NCH (I_/KI)

#if defined(__has_builtin)
#if __has_builtin(__builtin_amdgcn_exp2f)
#define EXP2F(v) __builtin_amdgcn_exp2f(v)
#endif
#endif
#ifndef EXP2F
#define EXP2F(v) exp2f(v)
#endif

// ---------------------------------------------------------------------------
// K1: partial KAN sums, i-range of 64 per block. kan4's proven per-thread
// structure (4 accs, scalar param staging, 40 VGPR) + double-buffered LDS
// with ONE barrier per chunk + 4-VALU eval. 2048 blocks = 8/CU = 32 waves/CU.
// XCD k (blockIdx&7) owns o in [64k, 64k+64): params L2-resident per XCD.
// ---------------------------------------------------------------------------
__global__ __launch_bounds__(256, 8) void kan8(
    const float* __restrict__ x, const float* __restrict__ scale,
    const float* __restrict__ bias, const float* __restrict__ weight,
    float* __restrict__ pY)
{
    __shared__ float Lx[2][KI][LXS];      // x transposed: [buf][i_local][b_local]
    __shared__ float Lp[2][KI][TO][4];    // [buf][i][o]{c, g, m, n}

    const int fid = blockIdx.x;
    const int xcd = fid & 7;
    const int seq = fid >> 3;              // 0..255
    const int ot  = xcd * 4 + (seq & 3);   // 0..31
    const int by  = (seq >> 2) & 7;        // 0..7
    const int iz  = seq >> 5;              // 0..7

    const int o0 = ot * TO;
    const int b0 = by * TB;
    const int z0 = iz * NIZ;

    const int t   = threadIdx.x;
    const int to  = t & (TO - 1);      // o within tile (eval)
    const int tb4 = t >> 4;            // b-quad (eval)
    const int lb  = t >> 2;            // x staging row
    const int lq  = t & 3;             // x staging i-quarter
    const int li  = t >> 4;            // param staging i
    const int lo  = t & 15;            // param staging o

    float acc0 = 0.f, acc1 = 0.f, acc2 = 0.f, acc3 = 0.f;

    float4 xv; float sc, bi, w;

#define GLOAD(CH)                                                          \
    {                                                                      \
        const int i0_ = z0 + (CH) * KI;                                    \
        xv = *reinterpret_cast<const float4*>(                             \
                 &x[(size_t)(b0 + lb) * I_ + i0_ + lq * 4]);               \
        const int pidx = (i0_ + li) * O_ + o0 + lo;                        \
        sc = scale[pidx]; bi = bias[pidx]; w = weight[pidx];               \
    }

#define SWRITE(BUF)                                                        \
    {                                                                      \
        Lx[BUF][lq * 4 + 0][lb] = xv.x;                                    \
        Lx[BUF][lq * 4 + 1][lb] = xv.y;                                    \
        Lx[BUF][lq * 4 + 2][lb] = xv.z;                                    \
        Lx[BUF][lq * 4 + 3][lb] = xv.w;                                    \
        const float c = SQH * __builtin_amdgcn_rcpf(sc);                   \
        Lp[BUF][li][lo][0] = c;                                            \
        Lp[BUF][li][lo][1] = -bi * c;                                      \
        Lp[BUF][li][lo][2] = MN_ * w;                                      \
        Lp[BUF][li][lo][3] = NN_ * w;                                      \
    }

#define EV(xr, aa)                                                         \
    {                                                                      \
        const float h  = fmaf((xr), p.x, p.y);                             \
        const float un = -h * h;                                           \
        const float e  = EXP2F(un);                                        \
        const float gg = fmaf(un, p.z, p.w);                               \
        (aa) = fmaf(gg, e, (aa));                                          \
    }

    GLOAD(0);
    SWRITE(0);

    #pragma unroll
    for (int ch = 0; ch < NCHZ; ++ch) {
        const int cur = ch & 1;
        if (ch + 1 < NCHZ) GLOAD(ch + 1);    // next chunk flies under eval
        __syncthreads();                     // buf[cur] visible; buf[cur^1] free
        #pragma unroll
        for (int ii = 0; ii < KI; ++ii) {
            const float4 p  = *reinterpret_cast<const float4*>(&Lp[cur][ii][to][0]);
            const float4 x4 = *reinterpret_cast<const float4*>(&Lx[cur][ii][tb4 * 4]);
            EV(x4.x, acc0);
            EV(x4.y, acc1);
            EV(x4.z, acc2);
            EV(x4.w, acc3);
        }
        if (ch + 1 < NCHZ) SWRITE(cur ^ 1);  // loads landed during eval
    }
#undef GLOAD
#undef SWRITE
#undef EV

    const size_t base = ((size_t)iz * B_ + b0 + tb4 * 4) * O_ + o0 + to;
    pY[base + 0 * O_] = acc0;
    pY[base + 1 * O_] = acc1;
    pY[base + 2 * O_] = acc2;
    pY[base + 3 * O_] = acc3;
}

// ---------------------------------------------------------------------------
// K2: fused 8-partial combine + BatchNorm stats + apply. 128 blocks, 4 o's
// each; o<->XCD mapping matches kan8 so pY reads hit the local L2.
// ---------------------------------------------------------------------------
__global__ __launch_bounds__(256) void comb_bn8(
    const float* __restrict__ pY,
    const float* __restrict__ gamma, const float* __restrict__ beta,
    float* __restrict__ y)
{
    __shared__ float Ws[4][8];
    __shared__ float Ac[8];

    const int bid = blockIdx.x;                       // 0..127
    const int o4  = (bid & 7) * 64 + (bid >> 3) * 4;  // XCD k owns o [64k,64k+64)
    const int t   = threadIdx.x;

    float4 v[2];
    float sx = 0.f, sy = 0.f, sz = 0.f, sw = 0.f;
    float qx = 0.f, qy = 0.f, qz = 0.f, qw = 0.f;
    #pragma unroll
    for (int r = 0; r < 2; ++r) {
        const int b = t + 256 * r;
        const size_t base = (size_t)b * O_ + o4;
        float4 a = *reinterpret_cast<const float4*>(&pY[base]);
        #pragma unroll
        for (int z = 1; z < ZN; ++z) {
            const float4 p = *reinterpret_cast<const float4*>(&pY[(size_t)z * BO_ + base]);
            a.x += p.x; a.y += p.y; a.z += p.z; a.w += p.w;
        }
        v[r] = a;
        sx += a.x; sy += a.y; sz += a.z; sw += a.w;
        qx += a.x * a.x; qy += a.y * a.y; qz += a.z * a.z; qw += a.w * a.w;
    }

    #pragma unroll
    for (int m = 1; m < 64; m <<= 1) {
        sx += __shfl_xor(sx, m); sy += __shfl_xor(sy, m);
        sz += __shfl_xor(sz, m); sw += __shfl_xor(sw, m);
        qx += __shfl_xor(qx, m); qy += __shfl_xor(qy, m);
        qz += __shfl_xor(qz, m); qw += __shfl_xor(qw, m);
    }
    if ((t & 63) == 0) {
        const int wv = t >> 6;
        Ws[wv][0] = sx; Ws[wv][1] = sy; Ws[wv][2] = sz; Ws[wv][3] = sw;
        Ws[wv][4] = qx; Ws[wv][5] = qy; Ws[wv][6] = qz; Ws[wv][7] = qw;
    }
    __syncthreads();
    if (t < 4) {
        const float s  = Ws[0][t]     + Ws[1][t]     + Ws[2][t]     + Ws[3][t];
        const float q  = Ws[0][t + 4] + Ws[1][t + 4] + Ws[2][t + 4] + Ws[3][t + 4];
        const float mean = s * (1.0f / B_);
        const float var  = q * (1.0f / B_) - mean * mean;
        const float inv  = rsqrtf(var + BN_EPS);
        const float a = gamma[o4 + t] * inv;
        Ac[t]     = a;
        Ac[t + 4] = fmaf(-mean, a, beta[o4 + t]);
    }
    __syncthreads();

    const float4 a4 = *reinterpret_cast<const float4*>(&Ac[0]);
    const float4 c4 = *reinterpret_cast<const float4*>(&Ac[4]);
    #pragma unroll
    for (int r = 0; r < 2; ++r) {
        const int b = t + 256 * r;
        float4 o;
        o.x = fmaf(v[r].x, a4.x, c4.x);
        o.y = fmaf(v[r].y, a4.y, c4.y);
        o.z = fmaf(v[r].z, a4.z, c4.z);
        o.w = fmaf(v[r].w, a4.w, c4.w);
        *reinterpret_cast<float4*>(&y[(size_t)b * O_ + o4]) = o;
    }
}

// ---------------------------------------------------------------------------
// Fallback path (Round-1 kernels, 32 KB ws) — used only if ws too small.
// ---------------------------------------------------------------------------
__global__ __launch_bounds__(256) void kan_main(
    const float* __restrict__ x, const float* __restrict__ scale,
    const float* __restrict__ bias, const float* __restrict__ weight,
    float* __restrict__ y, float* __restrict__ psum, float* __restrict__ psumsq)
{
    __shared__ float LxF[KI][LXS];
    __shared__ float Lp[KI][TO][4];
    __shared__ float Rs[2][TB/4][TO];

    const int t   = threadIdx.x;
    const int to  = t & (TO - 1);
    const int tb4 = t >> 4;
    const int o0  = blockIdx.x * TO;
    const int b0  = blockIdx.y * TB;
    const int lb = t >> 2;
    const int lq = t & 3;
    const int li = t >> 4;
    const int lo = t & 15;

    float acc0 = 0.f, acc1 = 0.f, acc2 = 0.f, acc3 = 0.f;

    for (int ch = 0; ch < NCH; ++ch) {
        const int i0 = ch * KI;
        const float4 xv = *reinterpret_cast<const float4*>(&x[(b0 + lb) * I_ + i0 + lq * 4]);
        const int pidx = (i0 + li) * O_ + o0 + lo;
        const float sc = scale[pidx];
        const float bi = bias[pidx];
        const float w  = weight[pidx];

        __syncthreads();
        LxF[lq * 4 + 0][lb] = xv.x;
        LxF[lq * 4 + 1][lb] = xv.y;
        LxF[lq * 4 + 2][lb] = xv.z;
        LxF[lq * 4 + 3][lb] = xv.w;
        const float rs = __builtin_amdgcn_rcpf(sc);
        Lp[li][lo][0] = rs;
        Lp[li][lo][1] = bi * rs;
        Lp[li][lo][2] = w;
        __syncthreads();

        #pragma unroll
        for (int ii = 0; ii < KI; ++ii) {
            const float4 p  = *reinterpret_cast<const float4*>(&Lp[ii][to][0]);
            const float4 xx = *reinterpret_cast<const float4*>(&LxF[ii][tb4 * 4]);
            {
                const float tt = fmaf(xx.x, p.x, -p.y);
                const float t2 = tt * tt;
                const float e  = EXP2F(t2 * K_EXP);
                const float g  = fmaf(t2, p.z, -p.z);
                acc0 = fmaf(g, e, acc0);
            }
            {
                const float tt = fmaf(xx.y, p.x, -p.y);
                const float t2 = tt * tt;
                const float e  = EXP2F(t2 * K_EXP);
                const float g  = fmaf(t2, p.z, -p.z);
                acc1 = fmaf(g, e, acc1);
            }
            {
                const float tt = fmaf(xx.z, p.x, -p.y);
                const float t2 = tt * tt;
                const float e  = EXP2F(t2 * K_EXP);
                const float g  = fmaf(t2, p.z, -p.z);
                acc2 = fmaf(g, e, acc2);
            }
            {
                const float tt = fmaf(xx.w, p.x, -p.y);
                const float t2 = tt * tt;
                const float e  = EXP2F(t2 * K_EXP);
                const float g  = fmaf(t2, p.z, -p.z);
                acc3 = fmaf(g, e, acc3);
            }
        }
    }

    const float y0 = NORM_ * acc0;
    const float y1 = NORM_ * acc1;
    const float y2 = NORM_ * acc2;
    const float y3 = NORM_ * acc3;

    const int brow = b0 + tb4 * 4;
    y[(brow + 0) * O_ + o0 + to] = y0;
    y[(brow + 1) * O_ + o0 + to] = y1;
    y[(brow + 2) * O_ + o0 + to] = y2;
    y[(brow + 3) * O_ + o0 + to] = y3;

    Rs[0][tb4][to] = y0 + y1 + y2 + y3;
    Rs[1][tb4][to] = y0 * y0 + y1 * y1 + y2 * y2 + y3 * y3;
    __syncthreads();
    if (t < TO) {
        float s = 0.f, s2 = 0.f;
        #pragma unroll
        for (int k = 0; k < TB / 4; ++k) {
            s  += Rs[0][k][t];
            s2 += Rs[1][k][t];
        }
        psum  [blockIdx.y * O_ + o0 + t] = s;
        psumsq[blockIdx.y * O_ + o0 + t] = s2;
    }
}

__global__ __launch_bounds__(256) void bn_apply(
    const float* __restrict__ psum, const float* __restrict__ psumsq,
    const float* __restrict__ gamma, const float* __restrict__ beta,
    float* __restrict__ y)
{
    const int o = blockIdx.x * 256 + threadIdx.x;
    float s = 0.f, s2 = 0.f;
    #pragma unroll
    for (int k = 0; k < B_ / TB; ++k) {
        s  += psum  [k * O_ + o];
        s2 += psumsq[k * O_ + o];
    }
    const float mean = s * (1.0f / B_);
    const float var  = s2 * (1.0f / B_) - mean * mean;
    const float inv  = rsqrtf(var + BN_EPS);
    const float a = gamma[o] * inv;
    const float c = fmaf(-mean, a, beta[o]);

    const int bstart = blockIdx.y * 16;
    #pragma unroll
    for (int b = bstart; b < bstart + 16; ++b) {
        const int idx = b * O_ + o;
        y[idx] = fmaf(y[idx], a, c);
    }
}

// ---------------------------------------------------------------------------

extern "C" void kernel_launch(void* const* d_in, const int* in_sizes, int n_in,
                              void* d_out, int out_size, void* d_ws, size_t ws_size,
                              hipStream_t stream) {
    const float* x      = (const float*)d_in[0];
    const float* scale  = (const float*)d_in[1];
    const float* bias   = (const float*)d_in[2];
    const float* weight = (const float*)d_in[3];
    const float* gamma  = (const float*)d_in[4];
    const float* beta   = (const float*)d_in[5];
    float* out = (float*)d_out;

    const size_t pY_b = (size_t)ZN * BO_ * sizeof(float);   // 8 MB

    if (ws_size >= pY_b) {
        float* pY = (float*)d_ws;
        kan8<<<32 * 8 * 8, 256, 0, stream>>>(x, scale, bias, weight, pY);  // 2048 blocks
        comb_bn8<<<O_ / 4, 256, 0, stream>>>(pY, gamma, beta, out);        // 128 blocks
    } else {
        float* psum   = (float*)d_ws;
        float* psumsq = psum + (B_ / TB) * O_;

        dim3 g1(O_ / TO, B_ / TB);
        kan_main<<<g1, 256, 0, stream>>>(x, scale, bias, weight, out, psum, psumsq);

        dim3 g2(O_ / 256, B_ / 16);
        bn_apply<<<g2, 256, 0, stream>>>(psum, psumsq, gamma, beta, out);
    }
}

// Round 7
// 32.970 us; speedup vs baseline: 15.6114x; 15.6114x over previous
//
#include <hip/hip_runtime.h>
#include <math.h>

#define B_ 512
#define I_ 512
#define O_ 512
#define BO_ (B_*O_)

// fast path
#define TB 64                  // b per block
#define TO 16                  // o per block
#define KI 16                  // i per chunk
#define ZN 8                   // i-splits
#define NIZ (I_/ZN)            // 64 i per block
#define NCHZ (NIZ/KI)          // 4 chunks
#define LXS (TB + 4)           // 68: padded x rows

#define SQH    0.84932180028801904f   // sqrt(0.5*log2(e))
#define MN_   (-1.2023679775792928f)  // -(2 ln2) * NORM
#define NN_   (-0.86732507058407750f) // -NORM
#define NORM_  (0.86732507058407750f)
#define K_EXP  (-0.72134752044448170f)
#define BN_EPS (1e-5f)
#define NCH (I_/KI)

#if defined(__has_builtin)
#if __has_builtin(__builtin_amdgcn_exp2f)
#define EXP2F(v) __builtin_amdgcn_exp2f(v)
#endif
#endif
#ifndef EXP2F
#define EXP2F(v) exp2f(v)
#endif

// ---------------------------------------------------------------------------
// K1: partial KAN sums, i-range of 64 per block. EXACT kan4 chunk structure
// (GLOAD; barrier; SWRITE; barrier; EVAL — staging regs live only briefly,
// NO launch-bounds occupancy cap -> no spill). 2048 blocks = 8/CU.
// XCD k (blockIdx&7) owns o in [64k, 64k+64): params L2-resident per XCD.
// Eval: 4 VALU + 1 transcendental per element (NORM folded into m,n).
// ---------------------------------------------------------------------------
__global__ __launch_bounds__(256) void kanZ(
    const float* __restrict__ x, const float* __restrict__ scale,
    const float* __restrict__ bias, const float* __restrict__ weight,
    float* __restrict__ pY)
{
    __shared__ float Lx[KI][LXS];      // x transposed: [i_local][b_local]
    __shared__ float Lp[KI][TO][4];    // [i][o]{c, g, m, n}

    const int fid = blockIdx.x;
    const int xcd = fid & 7;
    const int seq = fid >> 3;              // 0..255
    const int ot  = xcd * 4 + (seq & 3);   // 0..31
    const int by  = (seq >> 2) & 7;        // 0..7
    const int iz  = seq >> 5;              // 0..7

    const int o0 = ot * TO;
    const int b0 = by * TB;
    const int z0 = iz * NIZ;

    const int t   = threadIdx.x;
    const int to  = t & (TO - 1);      // o within tile (eval)
    const int tb4 = t >> 4;            // b-quad (eval)
    const int lb  = t >> 2;            // x staging row
    const int lq  = t & 3;             // x staging i-quarter
    const int li  = t >> 4;            // param staging i
    const int lo  = t & 15;            // param staging o

    float acc0 = 0.f, acc1 = 0.f, acc2 = 0.f, acc3 = 0.f;

    for (int ch = 0; ch < NCHZ; ++ch) {
        const int i0 = z0 + ch * KI;
        // issue global loads before the barrier so they overlap the wait
        const float4 xv = *reinterpret_cast<const float4*>(
            &x[(size_t)(b0 + lb) * I_ + i0 + lq * 4]);
        const int pidx = (i0 + li) * O_ + o0 + lo;
        const float sc = scale[pidx];
        const float bi = bias[pidx];
        const float w  = weight[pidx];

        __syncthreads();               // previous chunk fully consumed
        Lx[lq * 4 + 0][lb] = xv.x;
        Lx[lq * 4 + 1][lb] = xv.y;
        Lx[lq * 4 + 2][lb] = xv.z;
        Lx[lq * 4 + 3][lb] = xv.w;
        const float c = SQH * __builtin_amdgcn_rcpf(sc);
        Lp[li][lo][0] = c;
        Lp[li][lo][1] = -bi * c;
        Lp[li][lo][2] = MN_ * w;
        Lp[li][lo][3] = NN_ * w;
        __syncthreads();               // staging visible

        #pragma unroll
        for (int ii = 0; ii < KI; ++ii) {
            const float4 p  = *reinterpret_cast<const float4*>(&Lp[ii][to][0]);
            const float4 x4 = *reinterpret_cast<const float4*>(&Lx[ii][tb4 * 4]);
            {
                const float h  = fmaf(x4.x, p.x, p.y);
                const float un = -h * h;
                const float e  = EXP2F(un);
                const float gg = fmaf(un, p.z, p.w);
                acc0 = fmaf(gg, e, acc0);
            }
            {
                const float h  = fmaf(x4.y, p.x, p.y);
                const float un = -h * h;
                const float e  = EXP2F(un);
                const float gg = fmaf(un, p.z, p.w);
                acc1 = fmaf(gg, e, acc1);
            }
            {
                const float h  = fmaf(x4.z, p.x, p.y);
                const float un = -h * h;
                const float e  = EXP2F(un);
                const float gg = fmaf(un, p.z, p.w);
                acc2 = fmaf(gg, e, acc2);
            }
            {
                const float h  = fmaf(x4.w, p.x, p.y);
                const float un = -h * h;
                const float e  = EXP2F(un);
                const float gg = fmaf(un, p.z, p.w);
                acc3 = fmaf(gg, e, acc3);
            }
        }
    }

    const size_t base = ((size_t)iz * B_ + b0 + tb4 * 4) * O_ + o0 + to;
    pY[base + 0 * O_] = acc0;
    pY[base + 1 * O_] = acc1;
    pY[base + 2 * O_] = acc2;
    pY[base + 3 * O_] = acc3;
}

// ---------------------------------------------------------------------------
// K2: fused 8-partial combine + BatchNorm stats + apply. 128 blocks, 4 o's
// each; o<->XCD mapping matches kanZ so pY reads hit the local L2.
// ---------------------------------------------------------------------------
__global__ __launch_bounds__(256) void comb_bn8(
    const float* __restrict__ pY,
    const float* __restrict__ gamma, const float* __restrict__ beta,
    float* __restrict__ y)
{
    __shared__ float Ws[4][8];
    __shared__ float Ac[8];

    const int bid = blockIdx.x;                       // 0..127
    const int o4  = (bid & 7) * 64 + (bid >> 3) * 4;  // XCD k owns o [64k,64k+64)
    const int t   = threadIdx.x;

    float4 v[2];
    float sx = 0.f, sy = 0.f, sz = 0.f, sw = 0.f;
    float qx = 0.f, qy = 0.f, qz = 0.f, qw = 0.f;
    #pragma unroll
    for (int r = 0; r < 2; ++r) {
        const int b = t + 256 * r;
        const size_t base = (size_t)b * O_ + o4;
        float4 a = *reinterpret_cast<const float4*>(&pY[base]);
        #pragma unroll
        for (int z = 1; z < ZN; ++z) {
            const float4 p = *reinterpret_cast<const float4*>(&pY[(size_t)z * BO_ + base]);
            a.x += p.x; a.y += p.y; a.z += p.z; a.w += p.w;
        }
        v[r] = a;
        sx += a.x; sy += a.y; sz += a.z; sw += a.w;
        qx += a.x * a.x; qy += a.y * a.y; qz += a.z * a.z; qw += a.w * a.w;
    }

    #pragma unroll
    for (int m = 1; m < 64; m <<= 1) {
        sx += __shfl_xor(sx, m); sy += __shfl_xor(sy, m);
        sz += __shfl_xor(sz, m); sw += __shfl_xor(sw, m);
        qx += __shfl_xor(qx, m); qy += __shfl_xor(qy, m);
        qz += __shfl_xor(qz, m); qw += __shfl_xor(qw, m);
    }
    if ((t & 63) == 0) {
        const int wv = t >> 6;
        Ws[wv][0] = sx; Ws[wv][1] = sy; Ws[wv][2] = sz; Ws[wv][3] = sw;
        Ws[wv][4] = qx; Ws[wv][5] = qy; Ws[wv][6] = qz; Ws[wv][7] = qw;
    }
    __syncthreads();
    if (t < 4) {
        const float s  = Ws[0][t]     + Ws[1][t]     + Ws[2][t]     + Ws[3][t];
        const float q  = Ws[0][t + 4] + Ws[1][t + 4] + Ws[2][t + 4] + Ws[3][t + 4];
        const float mean = s * (1.0f / B_);
        const float var  = q * (1.0f / B_) - mean * mean;
        const float inv  = rsqrtf(var + BN_EPS);
        const float a = gamma[o4 + t] * inv;
        Ac[t]     = a;
        Ac[t + 4] = fmaf(-mean, a, beta[o4 + t]);
    }
    __syncthreads();

    const float4 a4 = *reinterpret_cast<const float4*>(&Ac[0]);
    const float4 c4 = *reinterpret_cast<const float4*>(&Ac[4]);
    #pragma unroll
    for (int r = 0; r < 2; ++r) {
        const int b = t + 256 * r;
        float4 o;
        o.x = fmaf(v[r].x, a4.x, c4.x);
        o.y = fmaf(v[r].y, a4.y, c4.y);
        o.z = fmaf(v[r].z, a4.z, c4.z);
        o.w = fmaf(v[r].w, a4.w, c4.w);
        *reinterpret_cast<float4*>(&y[(size_t)b * O_ + o4]) = o;
    }
}

// ---------------------------------------------------------------------------
// Fallback path (Round-1 kernels, 32 KB ws) — used only if ws too small.
// ---------------------------------------------------------------------------
__global__ __launch_bounds__(256) void kan_main(
    const float* __restrict__ x, const float* __restrict__ scale,
    const float* __restrict__ bias, const float* __restrict__ weight,
    float* __restrict__ y, float* __restrict__ psum, float* __restrict__ psumsq)
{
    __shared__ float LxF[KI][LXS];
    __shared__ float Lp[KI][TO][4];
    __shared__ float Rs[2][TB/4][TO];

    const int t   = threadIdx.x;
    const int to  = t & (TO - 1);
    const int tb4 = t >> 4;
    const int o0  = blockIdx.x * TO;
    const int b0  = blockIdx.y * TB;
    const int lb = t >> 2;
    const int lq = t & 3;
    const int li = t >> 4;
    const int lo = t & 15;

    float acc0 = 0.f, acc1 = 0.f, acc2 = 0.f, acc3 = 0.f;

    for (int ch = 0; ch < NCH; ++ch) {
        const int i0 = ch * KI;
        const float4 xv = *reinterpret_cast<const float4*>(&x[(b0 + lb) * I_ + i0 + lq * 4]);
        const int pidx = (i0 + li) * O_ + o0 + lo;
        const float sc = scale[pidx];
        const float bi = bias[pidx];
        const float w  = weight[pidx];

        __syncthreads();
        LxF[lq * 4 + 0][lb] = xv.x;
        LxF[lq * 4 + 1][lb] = xv.y;
        LxF[lq * 4 + 2][lb] = xv.z;
        LxF[lq * 4 + 3][lb] = xv.w;
        const float c = SQH * __builtin_amdgcn_rcpf(sc);
        Lp[li][lo][0] = c;
        Lp[li][lo][1] = -bi * c;
        Lp[li][lo][2] = MN_ * w;
        Lp[li][lo][3] = NN_ * w;
        __syncthreads();

        #pragma unroll
        for (int ii = 0; ii < KI; ++ii) {
            const float4 p  = *reinterpret_cast<const float4*>(&Lp[ii][to][0]);
            const float4 xx = *reinterpret_cast<const float4*>(&LxF[ii][tb4 * 4]);
            {
                const float h  = fmaf(xx.x, p.x, p.y);
                const float un = -h * h;
                const float e  = EXP2F(un);
                const float gg = fmaf(un, p.z, p.w);
                acc0 = fmaf(gg, e, acc0);
            }
            {
                const float h  = fmaf(xx.y, p.x, p.y);
                const float un = -h * h;
                const float e  = EXP2F(un);
                const float gg = fmaf(un, p.z, p.w);
                acc1 = fmaf(gg, e, acc1);
            }
            {
                const float h  = fmaf(xx.z, p.x, p.y);
                const float un = -h * h;
                const float e  = EXP2F(un);
                const float gg = fmaf(un, p.z, p.w);
                acc2 = fmaf(gg, e, acc2);
            }
            {
                const float h  = fmaf(xx.w, p.x, p.y);
                const float un = -h * h;
                const float e  = EXP2F(un);
                const float gg = fmaf(un, p.z, p.w);
                acc3 = fmaf(gg, e, acc3);
            }
        }
    }

    const int brow = b0 + tb4 * 4;
    y[(brow + 0) * O_ + o0 + to] = acc0;
    y[(brow + 1) * O_ + o0 + to] = acc1;
    y[(brow + 2) * O_ + o0 + to] = acc2;
    y[(brow + 3) * O_ + o0 + to] = acc3;

    Rs[0][tb4][to] = acc0 + acc1 + acc2 + acc3;
    Rs[1][tb4][to] = acc0 * acc0 + acc1 * acc1 + acc2 * acc2 + acc3 * acc3;
    __syncthreads();
    if (t < TO) {
        float s = 0.f, s2 = 0.f;
        #pragma unroll
        for (int k = 0; k < TB / 4; ++k) {
            s  += Rs[0][k][t];
            s2 += Rs[1][k][t];
        }
        psum  [blockIdx.y * O_ + o0 + t] = s;
        psumsq[blockIdx.y * O_ + o0 + t] = s2;
    }
}

__global__ __launch_bounds__(256) void bn_apply(
    const float* __restrict__ psum, const float* __restrict__ psumsq,
    const float* __restrict__ gamma, const float* __restrict__ beta,
    float* __restrict__ y)
{
    const int o = blockIdx.x * 256 + threadIdx.x;
    float s = 0.f, s2 = 0.f;
    #pragma unroll
    for (int k = 0; k < B_ / TB; ++k) {
        s  += psum  [k * O_ + o];
        s2 += psumsq[k * O_ + o];
    }
    const float mean = s * (1.0f / B_);
    const float var  = s2 * (1.0f / B_) - mean * mean;
    const float inv  = rsqrtf(var + BN_EPS);
    const float a = gamma[o] * inv;
    const float c = fmaf(-mean, a, beta[o]);

    const int bstart = blockIdx.y * 16;
    #pragma unroll
    for (int b = bstart; b < bstart + 16; ++b) {
        const int idx = b * O_ + o;
        y[idx] = fmaf(y[idx], a, c);
    }
}

// ---------------------------------------------------------------------------

extern "C" void kernel_launch(void* const* d_in, const int* in_sizes, int n_in,
                              void* d_out, int out_size, void* d_ws, size_t ws_size,
                              hipStream_t stream) {
    const float* x      = (const float*)d_in[0];
    const float* scale  = (const float*)d_in[1];
    const float* bias   = (const float*)d_in[2];
    const float* weight = (const float*)d_in[3];
    const float* gamma  = (const float*)d_in[4];
    const float* beta   = (const float*)d_in[5];
    float* out = (float*)d_out;

    const size_t pY_b = (size_t)ZN * BO_ * sizeof(float);   // 8 MB

    if (ws_size >= pY_b) {
        float* pY = (float*)d_ws;
        kanZ<<<32 * 8 * 8, 256, 0, stream>>>(x, scale, bias, weight, pY);  // 2048 blocks
        comb_bn8<<<O_ / 4, 256, 0, stream>>>(pY, gamma, beta, out);        // 128 blocks
    } else {
        float* psum   = (float*)d_ws;
        float* psumsq = psum + (B_ / TB) * O_;

        dim3 g1(O_ / TO, B_ / TB);
        kan_main<<<g1, 256, 0, stream>>>(x, scale, bias, weight, out, psum, psumsq);

        dim3 g2(O_ / 256, B_ / 16);
        bn_apply<<<g2, 256, 0, stream>>>(psum, psumsq, gamma, beta, out);
    }
}